// Round 17
// baseline (409.605 us; speedup 1.0000x reference)
//
#include <hip/hip_runtime.h>
#include <cstdint>
#include <cstddef>

#define BN_EPS 1e-5f

typedef unsigned short u16;
typedef __attribute__((ext_vector_type(8))) short bf16x8;   // 8 bf16 (4 VGPRs)
typedef __attribute__((ext_vector_type(4))) float f32x4;

constexpr int NN = 50000;
constexpr int NE = 800000;

__device__ __forceinline__ u16 f2bf(float f) {
    unsigned u = __float_as_uint(f);
    return (u16)((u + 0x7fffu + ((u >> 16) & 1u)) >> 16);   // RNE
}
__device__ __forceinline__ float bf2f(u16 h) { return __uint_as_float(((unsigned)h) << 16); }

// async global->LDS 16B DMA (dest = wave-uniform base + lane*16)
__device__ __forceinline__ void gload16(const u16* g, u16* l) {
    __builtin_amdgcn_global_load_lds(
        (const __attribute__((address_space(1))) void*)g,
        (__attribute__((address_space(3))) void*)l, 16, 0, 0);
}

// u16-index XOR swizzle within a 64-u16 (128 B) group
__device__ __forceinline__ int swz(int col_u16, int row) {
    return col_u16 ^ ((row & 7) << 3);
}

// ---------------- CSR build (edge_index arrives as int32) ----------------
__global__ void count_deg_kernel(const int* __restrict__ ei, int* __restrict__ deg, int E) {
    int e = blockIdx.x * blockDim.x + threadIdx.x;
    if (e >= E) return;
    int d = ei[E + e];
    if ((unsigned)d < (unsigned)NN) atomicAdd(&deg[d], 1);
}

__global__ __launch_bounds__(256) void block_reduce_kernel(const int* __restrict__ deg,
                                                           int* __restrict__ blockSum, int n) {
    __shared__ int red[256];
    int i = blockIdx.x * 256 + threadIdx.x;
    red[threadIdx.x] = (i < n) ? deg[i] : 0;
    __syncthreads();
    for (int s = 128; s > 0; s >>= 1) {
        if (threadIdx.x < s) red[threadIdx.x] += red[threadIdx.x + s];
        __syncthreads();
    }
    if (threadIdx.x == 0) blockSum[blockIdx.x] = red[0];
}

// fused: per-block scan of blockSum (redundant, L2-hot) + per-element scan.
__global__ __launch_bounds__(256) void block_scan_kernel(
    const int* deg, const int* __restrict__ blockSum,
    int* __restrict__ row_ptr, int* cursor, int n, int nb) {
    __shared__ int pre[256];
    __shared__ int lds[256];
    int t = threadIdx.x;
    int bv = (t < nb) ? blockSum[t] : 0;
    pre[t] = bv;
    int i = blockIdx.x * 256 + t;
    int v = (i < n) ? deg[i] : 0;
    lds[t] = v;
    __syncthreads();
    for (int off = 1; off < 256; off <<= 1) {
        int a = (t >= off) ? pre[t - off] : 0;
        int b = (t >= off) ? lds[t - off] : 0;
        __syncthreads();
        pre[t] += a;
        lds[t] += b;
        __syncthreads();
    }
    if (blockIdx.x == 0 && t == nb - 1) row_ptr[n] = pre[t];
    if (i < n) {
        int blockOff = (blockIdx.x == 0) ? 0 : pre[blockIdx.x - 1];
        int ex = blockOff + lds[t] - v;
        row_ptr[i] = ex;
        cursor[i] = ex;
    }
}

__global__ void fill_csr_kernel(const int* __restrict__ ei, const float* __restrict__ ew,
                                int* __restrict__ cursor, int2* __restrict__ csr_sw, int E) {
    int e = blockIdx.x * blockDim.x + threadIdx.x;
    if (e >= E) return;
    int d = ei[E + e];
    int s = ei[e];
    if ((unsigned)d >= (unsigned)NN || (unsigned)s >= (unsigned)NN) return;
    int pos = atomicAdd(&cursor[d], 1);
    if (pos < E) csr_sw[pos] = make_int2(s, __float_as_int(ew[e]));
}

// ---------------- mega-prep: cursor zero + x->bf16 + all weight prep, 1 dispatch ----------------
constexpr int P_O1 = NN;                      // xconvert items (NN*64)
constexpr int P_O2 = P_O1 + NN * 64;          // w1_0 split (128*256)
constexpr int P_O3 = P_O2 + 128 * 256;        // w2_0 bn split (256*256)
constexpr int P_O4 = P_O3 + 256 * 256;        // w1_1 split
constexpr int P_O5 = P_O4 + 256 * 256;        // w2_1 bn split
constexpr int P_O6 = P_O5 + 256 * 256;        // wpad (64*256)
constexpr int P_O7 = P_O6 + 64 * 256;         // bf0 (256)
constexpr int P_O8 = P_O7 + 256;              // bf1 (256)
constexpr int P_TOT = P_O8 + 256;

__global__ __launch_bounds__(256) void prep_kernel(
    const float* __restrict__ x,
    const float* __restrict__ w1_0, const float* __restrict__ w2_0,
    const float* __restrict__ w1_1, const float* __restrict__ w2_1,
    const float* __restrict__ w1_2,
    const float* __restrict__ b2_0, const float* __restrict__ bng0,
    const float* __restrict__ bnb0, const float* __restrict__ bnm0, const float* __restrict__ bnv0,
    const float* __restrict__ b2_1, const float* __restrict__ bng1,
    const float* __restrict__ bnb1, const float* __restrict__ bnm1, const float* __restrict__ bnv1,
    int* __restrict__ cursor, u16* __restrict__ xbf,
    u16* __restrict__ w10h, u16* __restrict__ w10l,
    u16* __restrict__ w20h, u16* __restrict__ w20l,
    u16* __restrict__ w11h, u16* __restrict__ w11l,
    u16* __restrict__ w21h, u16* __restrict__ w21l,
    u16* __restrict__ wph,  u16* __restrict__ wpl,
    float* __restrict__ bf0, float* __restrict__ bf1) {
    int i = blockIdx.x * 256 + threadIdx.x;
    if (i >= P_TOT) return;
    if (i >= P_O1 && i < P_O2) {          // x -> bf16 swizzled, 2 cols/item
        int j = i - P_O1;
        int node = j >> 6, col = (j & 63) * 2;
        float2 v = *(const float2*)(x + (size_t)node * 128 + col);
        ushort2 h; h.x = f2bf(v.x); h.y = f2bf(v.y);
        *(ushort2*)(xbf + (size_t)node * 128 + swz(col, node)) = h;
    } else if (i < P_O1) {                // cursor zero
        cursor[i] = 0;
    } else if (i < P_O3) {                // w1_0: [128][256] -> T split swizzled
        int j = i - P_O2;
        int k = j >> 8, n = j & 255;
        float v = w1_0[j];
        u16 h = f2bf(v);
        size_t o = (size_t)n * 128 + swz(k, n);
        w10h[o] = h; w10l[o] = f2bf(v - bf2f(h));
    } else if (i < P_O4) {                // w2_0 * bn0 scale
        int j = i - P_O3;
        int k = j >> 8, n = j & 255;
        float sc = bng0[n] * rsqrtf(bnv0[n] + BN_EPS);
        float v = w2_0[j] * sc;
        u16 h = f2bf(v);
        size_t o = (size_t)n * 256 + swz(k, n);
        w20h[o] = h; w20l[o] = f2bf(v - bf2f(h));
    } else if (i < P_O5) {                // w1_1
        int j = i - P_O4;
        int k = j >> 8, n = j & 255;
        float v = w1_1[j];
        u16 h = f2bf(v);
        size_t o = (size_t)n * 256 + swz(k, n);
        w11h[o] = h; w11l[o] = f2bf(v - bf2f(h));
    } else if (i < P_O6) {                // w2_1 * bn1 scale
        int j = i - P_O5;
        int k = j >> 8, n = j & 255;
        float sc = bng1[n] * rsqrtf(bnv1[n] + BN_EPS);
        float v = w2_1[j] * sc;
        u16 h = f2bf(v);
        size_t o = (size_t)n * 256 + swz(k, n);
        w21h[o] = h; w21l[o] = f2bf(v - bf2f(h));
    } else if (i < P_O7) {                // w1_2 padded transposed [64][256]
        int j = i - P_O6;
        int n = j >> 8, k = j & 255;
        float v = (n < 40) ? w1_2[k * 40 + n] : 0.f;
        u16 h = f2bf(v);
        size_t o = (size_t)n * 256 + swz(k, n);
        wph[o] = h; wpl[o] = f2bf(v - bf2f(h));
    } else if (i < P_O8) {                // folded bias 0
        int n = i - P_O7;
        float sc = bng0[n] * rsqrtf(bnv0[n] + BN_EPS);
        bf0[n] = (b2_0[n] - bnm0[n]) * sc + bnb0[n];
    } else {                              // folded bias 1
        int n = i - P_O8;
        float sc = bng1[n] * rsqrtf(bnv1[n] + BN_EPS);
        bf1[n] = (b2_1[n] - bnm1[n]) * sc + bnb1[n];
    }
}

// ---------------- pull aggregation (C=128/256, bf16 pre-swizzled planes) ----------------
// node0: node-range offset (agg256 runs as two half dispatches for profiler visibility)
template <int C>
__global__ __launch_bounds__(256) void aggregate_kernel(
    const u16* __restrict__ xp,
    const int* __restrict__ row_ptr, const int2* __restrict__ csw,
    u16* __restrict__ outp, int node0, int n) {
    constexpr int V = (C == 128) ? 2 : 4;
    int node = node0 + blockIdx.x * 4 + (threadIdx.x >> 6);
    if (node >= n) return;
    int lane = threadIdx.x & 63;
    int col = lane * V;
    int beg = row_ptr[node], end = row_ptr[node + 1];

    float acc[V];
    if constexpr (C == 128) {
        ushort2 h = *(const ushort2*)(xp + (size_t)node * C + swz(col, node));
        acc[0] = bf2f(h.x); acc[1] = bf2f(h.y);
    } else {
        ushort4 h = *(const ushort4*)(xp + (size_t)node * C + swz(col, node));
        acc[0] = bf2f(h.x); acc[1] = bf2f(h.y); acc[2] = bf2f(h.z); acc[3] = bf2f(h.w);
    }

    int e = beg;
    // ---- 8-deep batch ----
    for (; e + 8 <= end; e += 8) {
        int2 sw[8];
#pragma unroll
        for (int u = 0; u < 8; u++) sw[u] = csw[e + u];
        if constexpr (C == 128) {
            ushort2 H[8];
#pragma unroll
            for (int u = 0; u < 8; u++) {
                int s = sw[u].x;
                H[u] = *(const ushort2*)(xp + (size_t)s * C + swz(col, s));
            }
#pragma unroll
            for (int u = 0; u < 8; u++) {
                float w = __int_as_float(sw[u].y);
                acc[0] = fmaf(w, bf2f(H[u].x), acc[0]);
                acc[1] = fmaf(w, bf2f(H[u].y), acc[1]);
            }
        } else {
            ushort4 H[8];
#pragma unroll
            for (int u = 0; u < 8; u++) {
                int s = sw[u].x;
                H[u] = *(const ushort4*)(xp + (size_t)s * C + swz(col, s));
            }
#pragma unroll
            for (int u = 0; u < 8; u++) {
                float w = __int_as_float(sw[u].y);
                acc[0] = fmaf(w, bf2f(H[u].x), acc[0]);
                acc[1] = fmaf(w, bf2f(H[u].y), acc[1]);
                acc[2] = fmaf(w, bf2f(H[u].z), acc[2]);
                acc[3] = fmaf(w, bf2f(H[u].w), acc[3]);
            }
        }
    }
    // ---- 4-deep batch ----
    for (; e + 4 <= end; e += 4) {
        int2 sw[4];
#pragma unroll
        for (int u = 0; u < 4; u++) sw[u] = csw[e + u];
        if constexpr (C == 128) {
            ushort2 H[4];
#pragma unroll
            for (int u = 0; u < 4; u++) {
                int s = sw[u].x;
                H[u] = *(const ushort2*)(xp + (size_t)s * C + swz(col, s));
            }
#pragma unroll
            for (int u = 0; u < 4; u++) {
                float w = __int_as_float(sw[u].y);
                acc[0] = fmaf(w, bf2f(H[u].x), acc[0]);
                acc[1] = fmaf(w, bf2f(H[u].y), acc[1]);
            }
        } else {
            ushort4 H[4];
#pragma unroll
            for (int u = 0; u < 4; u++) {
                int s = sw[u].x;
                H[u] = *(const ushort4*)(xp + (size_t)s * C + swz(col, s));
            }
#pragma unroll
            for (int u = 0; u < 4; u++) {
                float w = __int_as_float(sw[u].y);
                acc[0] = fmaf(w, bf2f(H[u].x), acc[0]);
                acc[1] = fmaf(w, bf2f(H[u].y), acc[1]);
                acc[2] = fmaf(w, bf2f(H[u].z), acc[2]);
                acc[3] = fmaf(w, bf2f(H[u].w), acc[3]);
            }
        }
    }
    // ---- scalar tail ----
    for (; e < end; ++e) {
        int2 sw = csw[e];
        float w = __int_as_float(sw.y);
        if constexpr (C == 128) {
            ushort2 h = *(const ushort2*)(xp + (size_t)sw.x * C + swz(col, sw.x));
            acc[0] = fmaf(w, bf2f(h.x), acc[0]); acc[1] = fmaf(w, bf2f(h.y), acc[1]);
        } else {
            ushort4 h = *(const ushort4*)(xp + (size_t)sw.x * C + swz(col, sw.x));
            acc[0] = fmaf(w, bf2f(h.x), acc[0]); acc[1] = fmaf(w, bf2f(h.y), acc[1]);
            acc[2] = fmaf(w, bf2f(h.z), acc[2]); acc[3] = fmaf(w, bf2f(h.w), acc[3]);
        }
    }

    if constexpr (C == 128) {
        ushort2 h;
        h.x = f2bf(acc[0]); h.y = f2bf(acc[1]);
        *(ushort2*)(outp + (size_t)node * C + swz(col, node)) = h;
    } else {
        ushort4 h;
        h.x = f2bf(acc[0]); h.y = f2bf(acc[1]); h.z = f2bf(acc[2]); h.w = f2bf(acc[3]);
        *(ushort4*)(outp + (size_t)node * C + swz(col, node)) = h;
    }
}

// ---------------- bf16-A x split-B MFMA GEMM ----------------
// Grid is (N-blocks, M-blocks): n-block fastest in dispatch order, so the 2 blocks
// sharing one A-tile are ADJACENT -> A-tile L2-hit on second read (halves A traffic).
template <int BN_, int EPI, int OUTHL>
__global__ __launch_bounds__(256, 3) void gemm_mfma_kernel(
    const u16* __restrict__ Ahi,
    const u16* __restrict__ Bhi, const u16* __restrict__ Blo,
    float* __restrict__ outf, u16* __restrict__ outhi,
    int M, int K, int LDA, int LDC, int NSTORE,
    const float* __restrict__ bias) {
    constexpr int WGN = (BN_ == 128) ? 2 : 1;
    constexpr int WGM = 4 / WGN;
    constexpr int WTM = 128 / WGM;
    constexpr int MF = WTM / 16;
    constexpr int NF = 4;
    __shared__ __attribute__((aligned(16))) u16 LA[128 * 64];
    __shared__ __attribute__((aligned(16))) u16 LB[2 * BN_ * 64];

    const int tid = threadIdx.x;
    const int lane = tid & 63;
    const int wid = tid >> 6;
    const int wm = wid / WGN, wn = wid % WGN;
    const int m0 = blockIdx.y * 128, n0 = blockIdx.x * BN_;
    const int ln = lane & 15, l4 = lane >> 4;

    f32x4 acc[MF][NF];
#pragma unroll
    for (int mi = 0; mi < MF; mi++)
#pragma unroll
        for (int ni = 0; ni < NF; ni++) acc[mi][ni] = (f32x4){0.f, 0.f, 0.f, 0.f};

    for (int k0 = 0; k0 < K; k0 += 64) {
#pragma unroll
        for (int rep = 0; rep < 4; rep++) {
            int idx = rep * 256 + tid;
            int row = idx >> 3, c16 = idx & 7;
            int gm = m0 + row;
            if (gm > M - 1) gm = M - 1;
            gload16(Ahi + (size_t)gm * LDA + k0 + c16 * 8, &LA[(size_t)(idx - lane) * 8]);
        }
#pragma unroll
        for (int rep = 0; rep < BN_ / 16; rep++) {
            int idx = rep * 256 + tid;
            int plane = idx / (BN_ * 8);
            int rc = idx % (BN_ * 8);
            int row = rc >> 3, c16 = rc & 7;
            const u16* src = plane ? Blo : Bhi;
            gload16(src + (size_t)(n0 + row) * K + k0 + c16 * 8, &LB[(size_t)(idx - lane) * 8]);
        }
        asm volatile("s_waitcnt vmcnt(0)" ::: "memory");
        __syncthreads();

#pragma unroll
        for (int kk = 0; kk < 2; kk++) {
            bf16x8 ah[MF], bh[NF], bl[NF];
#pragma unroll
            for (int mi = 0; mi < MF; mi++) {
                int row = wm * WTM + mi * 16 + ln;
                int slot = (kk * 4 + l4) ^ (row & 7);
                ah[mi] = *(const bf16x8*)&LA[row * 64 + slot * 8];
            }
#pragma unroll
            for (int ni = 0; ni < NF; ni++) {
                int row = wn * 64 + ni * 16 + ln;
                int slot = (kk * 4 + l4) ^ (row & 7);
                bh[ni] = *(const bf16x8*)&LB[row * 64 + slot * 8];
                bl[ni] = *(const bf16x8*)&LB[BN_ * 64 + row * 64 + slot * 8];
            }
#pragma unroll
            for (int mi = 0; mi < MF; mi++)
#pragma unroll
                for (int ni = 0; ni < NF; ni++) {
                    acc[mi][ni] = __builtin_amdgcn_mfma_f32_16x16x32_bf16(ah[mi], bh[ni], acc[mi][ni], 0, 0, 0);
                    acc[mi][ni] = __builtin_amdgcn_mfma_f32_16x16x32_bf16(ah[mi], bl[ni], acc[mi][ni], 0, 0, 0);
                }
        }
        __syncthreads();
    }

#pragma unroll
    for (int ni = 0; ni < NF; ni++) {
        int c = n0 + wn * 64 + ni * 16 + ln;
        float bb = 0.f;
        if constexpr (EPI == 1) bb = bias[c];
        bool cok = (c < NSTORE);
#pragma unroll
        for (int mi = 0; mi < MF; mi++) {
#pragma unroll
            for (int r = 0; r < 4; r++) {
                int row = m0 + wm * WTM + mi * 16 + l4 * 4 + r;
                if (row < M && cok) {
                    float v = acc[mi][ni][r] + bb;
                    if constexpr (EPI == 1) v = fmaxf(v, 0.f);
                    if constexpr (OUTHL == 1) {
                        outhi[(size_t)row * LDC + swz(c, row)] = f2bf(v);
                    } else if constexpr (OUTHL == 2) {
                        size_t o = (size_t)row * LDC + c;
                        outf[o] = v;
                        outhi[o] = f2bf(v);
                    } else {
                        outf[(size_t)row * LDC + c] = v;
                    }
                }
            }
        }
    }
}

// ---------------- fused agg<40> + tail: 6-way edge-parallel gather + shuffle softmax ----------------
__global__ __launch_bounds__(256) void agg40_final_kernel(
    const float* __restrict__ p, const u16* __restrict__ pbf,
    const int* __restrict__ row_ptr, const int2* __restrict__ csw,
    const float* __restrict__ b1, const float* __restrict__ w2,
    const float* __restrict__ b2, float* __restrict__ out, int n) {
    __shared__ float sw[1600], sb1[40], sb2[40];
    __shared__ float tl[4][40];
    for (int i = threadIdx.x; i < 1600; i += 256) sw[i] = w2[i];
    if (threadIdx.x < 40) { sb1[threadIdx.x] = b1[threadIdx.x]; sb2[threadIdx.x] = b2[threadIdx.x]; }
    __syncthreads();

    int w = threadIdx.x >> 6;
    int node = blockIdx.x * 4 + w;
    int lane = threadIdx.x & 63;
    bool valid = node < n;

    int g = lane / 10;
    int cl = lane - g * 10;
    int col = cl * 4;
    float a0 = 0.f, a1 = 0.f, a2 = 0.f, a3 = 0.f;
    if (valid && lane < 60) {
        int beg = row_ptr[node], end = row_ptr[node + 1];
        if (g == 0) {
            float4 sv = *(const float4*)(p + (size_t)node * 40 + col);
            a0 = sv.x; a1 = sv.y; a2 = sv.z; a3 = sv.w;
        }
        int e = beg + g;
        for (; e + 6 < end; e += 12) {
            int2 s0 = csw[e], s1 = csw[e + 6];
            ushort4 h0 = *(const ushort4*)(pbf + (size_t)s0.x * 40 + col);
            ushort4 h1 = *(const ushort4*)(pbf + (size_t)s1.x * 40 + col);
            float w0 = __int_as_float(s0.y), w1 = __int_as_float(s1.y);
            a0 = fmaf(w0, bf2f(h0.x), a0); a1 = fmaf(w0, bf2f(h0.y), a1);
            a2 = fmaf(w0, bf2f(h0.z), a2); a3 = fmaf(w0, bf2f(h0.w), a3);
            a0 = fmaf(w1, bf2f(h1.x), a0); a1 = fmaf(w1, bf2f(h1.y), a1);
            a2 = fmaf(w1, bf2f(h1.z), a2); a3 = fmaf(w1, bf2f(h1.w), a3);
        }
        for (; e < end; e += 6) {
            int2 s0 = csw[e];
            ushort4 h0 = *(const ushort4*)(pbf + (size_t)s0.x * 40 + col);
            float w0 = __int_as_float(s0.y);
            a0 = fmaf(w0, bf2f(h0.x), a0); a1 = fmaf(w0, bf2f(h0.y), a1);
            a2 = fmaf(w0, bf2f(h0.z), a2); a3 = fmaf(w0, bf2f(h0.w), a3);
        }
    }
    a0 += __shfl_down(a0, 30, 64);
    a1 += __shfl_down(a1, 30, 64);
    a2 += __shfl_down(a2, 30, 64);
    a3 += __shfl_down(a3, 30, 64);
    {
        float b0 = __shfl_down(a0, 10, 64), c0 = __shfl_down(a0, 20, 64);
        float b1v = __shfl_down(a1, 10, 64), c1 = __shfl_down(a1, 20, 64);
        float b2v = __shfl_down(a2, 10, 64), c2 = __shfl_down(a2, 20, 64);
        float b3 = __shfl_down(a3, 10, 64), c3 = __shfl_down(a3, 20, 64);
        a0 += b0 + c0;
        a1 += b1v + c1;
        a2 += b2v + c2;
        a3 += b3 + c3;
    }
    if (valid && lane < 10) {
        tl[w][col + 0] = fmaxf(a0 + sb1[col + 0], 0.f);
        tl[w][col + 1] = fmaxf(a1 + sb1[col + 1], 0.f);
        tl[w][col + 2] = fmaxf(a2 + sb1[col + 2], 0.f);
        tl[w][col + 3] = fmaxf(a3 + sb1[col + 3], 0.f);
    }
    __syncthreads();

    float y = -1e30f;
    if (valid && lane < 40) {
        y = sb2[lane];
#pragma unroll 8
        for (int k = 0; k < 40; k++) y = fmaf(tl[w][k], sw[k * 40 + lane], y);
    }
    float m = y;
#pragma unroll
    for (int o = 32; o > 0; o >>= 1) m = fmaxf(m, __shfl_xor(m, o, 64));
    float ex = (lane < 40) ? expf(y - m) : 0.f;
    float s = ex;
#pragma unroll
    for (int o = 32; o > 0; o >>= 1) s += __shfl_xor(s, o, 64);
    if (valid && lane < 40)
        out[(size_t)node * 40 + lane] = y - m - logf(s);
}

extern "C" void kernel_launch(void* const* d_in, const int* in_sizes, int n_in,
                              void* d_out, int out_size, void* d_ws, size_t ws_size,
                              hipStream_t stream) {
    const float* x    = (const float*)d_in[0];
    const int*   ei   = (const int*)d_in[1];  // int64 in ref -> int32 on device
    const float* ew   = (const float*)d_in[2];
    const float* w1_0 = (const float*)d_in[3],  *b1_0 = (const float*)d_in[4];
    const float* w2_0 = (const float*)d_in[5],  *b2_0 = (const float*)d_in[6];
    const float* w1_1 = (const float*)d_in[7],  *b1_1 = (const float*)d_in[8];
    const float* w2_1 = (const float*)d_in[9],  *b2_1 = (const float*)d_in[10];
    const float* w1_2 = (const float*)d_in[11], *b1_2 = (const float*)d_in[12];
    const float* w2_2 = (const float*)d_in[13], *b2_2 = (const float*)d_in[14];
    const float* bng0 = (const float*)d_in[15], *bnb0 = (const float*)d_in[16];
    const float* bnm0 = (const float*)d_in[17], *bnv0 = (const float*)d_in[18];
    const float* bng1 = (const float*)d_in[19], *bnb1 = (const float*)d_in[20];
    const float* bnm1 = (const float*)d_in[21], *bnv1 = (const float*)d_in[22];
    float* out = (float*)d_out;

    char* wsp = (char*)d_ws;
    size_t off = 0;
    auto alloc = [&](size_t bytes) -> char* {
        char* p = wsp + off;
        off += (bytes + 255) & ~(size_t)255;
        return p;
    };
    int*   cursor   = (int*)alloc((size_t)NN * sizeof(int));
    int*   row_ptr  = (int*)alloc((size_t)(NN + 1) * sizeof(int));
    int*   blockSum = (int*)alloc(256 * sizeof(int));
    int2*  csr_sw   = (int2*)alloc((size_t)NE * sizeof(int2));
    u16* xbf   = (u16*)alloc((size_t)NN * 128 * sizeof(u16));
    u16* h0agg = (u16*)alloc((size_t)NN * 128 * sizeof(u16));
    u16* bufA  = (u16*)alloc((size_t)NN * 256 * sizeof(u16));
    u16* bufB  = (u16*)alloc((size_t)NN * 256 * sizeof(u16));
    u16* w10h = (u16*)alloc(128 * 256 * 2); u16* w10l = (u16*)alloc(128 * 256 * 2);
    u16* w20h = (u16*)alloc(256 * 256 * 2); u16* w20l = (u16*)alloc(256 * 256 * 2);
    u16* w11h = (u16*)alloc(256 * 256 * 2); u16* w11l = (u16*)alloc(256 * 256 * 2);
    u16* w21h = (u16*)alloc(256 * 256 * 2); u16* w21l = (u16*)alloc(256 * 256 * 2);
    u16* wph  = (u16*)alloc(64 * 256 * 2);  u16* wpl  = (u16*)alloc(64 * 256 * 2);
    float* bf0 = (float*)alloc(256 * sizeof(float));
    float* bf1 = (float*)alloc(256 * sizeof(float));

    const int NB = (NN + 255) / 256;  // 196

    // --- 1 dispatch: cursor zero + x convert + all weight prep ---
    prep_kernel<<<(P_TOT + 255) / 256, 256, 0, stream>>>(
        x, w1_0, w2_0, w1_1, w2_1, w1_2,
        b2_0, bng0, bnb0, bnm0, bnv0,
        b2_1, bng1, bnb1, bnm1, bnv1,
        cursor, xbf, w10h, w10l, w20h, w20l, w11h, w11l, w21h, w21l,
        wph, wpl, bf0, bf1);

    // --- CSR build (4 dispatches) ---
    count_deg_kernel<<<(NE + 255) / 256, 256, 0, stream>>>(ei, cursor, NE);
    block_reduce_kernel<<<NB, 256, 0, stream>>>(cursor, blockSum, NN);
    block_scan_kernel<<<NB, 256, 0, stream>>>(cursor, blockSum, row_ptr, cursor, NN, NB);
    fill_csr_kernel<<<(NE + 255) / 256, 256, 0, stream>>>(ei, ew, cursor, csr_sw, NE);

    const int aggBlocks = (NN + 3) / 4;
    const int NHALF = 25000;                    // agg256 split point (visibility)
    const int aggHalfBlocks = NHALF / 4;        // 6250
    dim3 gBig(2, (NN + 127) / 128);             // n-block fastest: A-tile pair adjacent
    dim3 gSm(1, (NN + 127) / 128);

    // ---- layer 0 ----
    aggregate_kernel<128><<<aggBlocks, 256, 0, stream>>>(xbf, row_ptr, csr_sw, h0agg, 0, NN);
    gemm_mfma_kernel<128, 1, 1><<<gBig, 256, 0, stream>>>(
        h0agg, w10h, w10l, nullptr, bufA, NN, 128, 128, 256, 256, b1_0);
    gemm_mfma_kernel<128, 1, 1><<<gBig, 256, 0, stream>>>(
        bufA, w20h, w20l, nullptr, bufB, NN, 256, 256, 256, 256, bf0);

    // ---- layer 1 ---- (agg256 split into 2 half dispatches)
    aggregate_kernel<256><<<aggHalfBlocks, 256, 0, stream>>>(bufB, row_ptr, csr_sw, bufA, 0, NN);
    aggregate_kernel<256><<<aggBlocks - aggHalfBlocks, 256, 0, stream>>>(
        bufB, row_ptr, csr_sw, bufA, NHALF, NN);
    gemm_mfma_kernel<128, 1, 1><<<gBig, 256, 0, stream>>>(
        bufA, w11h, w11l, nullptr, bufB, NN, 256, 256, 256, 256, b1_1);
    gemm_mfma_kernel<128, 1, 1><<<gBig, 256, 0, stream>>>(
        bufB, w21h, w21l, nullptr, bufA, NN, 256, 256, 256, 256, bf1);

    // ---- layer 2 (reordered: p = h @ w1_2, then fused agg40+tail) ----
    float* p   = (float*)bufB;
    u16*   pbf = bufB + 4194304;             // 8 MB offset (u16 elements)
    gemm_mfma_kernel<64, 0, 2><<<gSm, 256, 0, stream>>>(
        bufA, wph, wpl, p, pbf, NN, 256, 256, 40, 40, nullptr);
    agg40_final_kernel<<<aggBlocks, 256, 0, stream>>>(
        p, pbf, row_ptr, csr_sw, b1_2, w2_2, b2_2, out, NN);
}

// Round 18
// 341.693 us; speedup vs baseline: 1.1988x; 1.1988x over previous
//
#include <hip/hip_runtime.h>
#include <cstdint>
#include <cstddef>

#define BN_EPS 1e-5f

typedef unsigned short u16;
typedef __attribute__((ext_vector_type(8))) short bf16x8;   // 8 bf16 (4 VGPRs)
typedef __attribute__((ext_vector_type(4))) float f32x4;

constexpr int NN = 50000;
constexpr int NE = 800000;
constexpr int NBUK = 256;          // dest buckets
constexpr int NPB  = 196;          // nodes per bucket (256*196 = 50176 >= NN)
constexpr int CAP  = 5000;         // bucket capacity (mean 3125, +33 sigma)
constexpr int EPB  = 2048;         // edges per partition block

__device__ __forceinline__ u16 f2bf(float f) {
    unsigned u = __float_as_uint(f);
    return (u16)((u + 0x7fffu + ((u >> 16) & 1u)) >> 16);   // RNE
}
__device__ __forceinline__ float bf2f(u16 h) { return __uint_as_float(((unsigned)h) << 16); }

// async global->LDS 16B DMA (dest = wave-uniform base + lane*16)
__device__ __forceinline__ void gload16(const u16* g, u16* l) {
    __builtin_amdgcn_global_load_lds(
        (const __attribute__((address_space(1))) void*)g,
        (__attribute__((address_space(3))) void*)l, 16, 0, 0);
}

// u16-index XOR swizzle within a 64-u16 (128 B) group
__device__ __forceinline__ int swz(int col_u16, int row) {
    return col_u16 ^ ((row & 7) << 3);
}

// ---------------- CSR build pass 1: binned partition ----------------
// One global atomic per (block,bucket); per-block contiguous runs into bucket regions.
__global__ __launch_bounds__(256) void partition_kernel(
    const int* __restrict__ ei, const float* __restrict__ ew,
    int* __restrict__ gcnt, int2* __restrict__ bbuf, int E) {
    __shared__ int lcnt[256], lbase[256], lcur[256];
    int t = threadIdx.x;
    lcnt[t] = 0;
    __syncthreads();
    int e0 = blockIdx.x * EPB;
#pragma unroll
    for (int i = 0; i < EPB / 256; i++) {
        int e = e0 + i * 256 + t;
        if (e < E) {
            int d = ei[E + e];
            if ((unsigned)d < (unsigned)NN) atomicAdd(&lcnt[d / NPB], 1);
        }
    }
    __syncthreads();
    lbase[t] = atomicAdd(&gcnt[t], lcnt[t]);
    lcur[t] = 0;
    __syncthreads();
#pragma unroll
    for (int i = 0; i < EPB / 256; i++) {
        int e = e0 + i * 256 + t;
        if (e < E) {
            int d = ei[E + e], s = ei[e];
            if ((unsigned)d < (unsigned)NN && (unsigned)s < (unsigned)NN) {
                int bin = d / NPB;
                int ld = d - bin * NPB;
                int r = atomicAdd(&lcur[bin], 1);
                int pos = lbase[bin] + r;
                if (pos < CAP)
                    bbuf[(size_t)bin * CAP + pos] = make_int2((ld << 16) | s, __float_as_int(ew[e]));
            }
        }
    }
}

// ---------------- CSR build pass 2: per-bucket sort + row_ptr ----------------
// One block per bucket. Writes CSR span (contiguous ~25KB, L2-resident) + row_ptr.
__global__ __launch_bounds__(256) void bucket_sort_kernel(
    const int* __restrict__ gcnt, const int2* __restrict__ bbuf,
    int* __restrict__ row_ptr, int2* __restrict__ csr_sw) {
    __shared__ int sg[256];
    __shared__ int deg[256];
    __shared__ int exl[256];
    __shared__ int lcur[256];
    int t = threadIdx.x, b = blockIdx.x;
    sg[t] = gcnt[t];
    deg[t] = 0;
    __syncthreads();
    for (int off = 1; off < 256; off <<= 1) {
        int u = (t >= off) ? sg[t - off] : 0;
        __syncthreads();
        sg[t] += u;
        __syncthreads();
    }
    int csr_start = (b == 0) ? 0 : sg[b - 1];
    int cnt_b = sg[b] - csr_start;
    // histogram local dests
    for (int i = t; i < cnt_b; i += 256) {
        int ld = ((unsigned)bbuf[(size_t)b * CAP + i].x) >> 16;
        atomicAdd(&deg[ld], 1);
    }
    __syncthreads();
    exl[t] = deg[t];
    __syncthreads();
    for (int off = 1; off < 256; off <<= 1) {
        int u = (t >= off) ? exl[t - off] : 0;
        __syncthreads();
        exl[t] += u;
        __syncthreads();
    }
    int my_excl = exl[t] - deg[t];
    int node = b * NPB + t;
    if (t < NPB && node < NN) row_ptr[node] = csr_start + my_excl;
    if (b == NBUK - 1 && t == 255) row_ptr[NN] = sg[255];
    __syncthreads();
    exl[t] = my_excl;       // rewrite as exclusive for scatter
    lcur[t] = 0;
    __syncthreads();
    for (int i = t; i < cnt_b; i += 256) {
        int2 ev = bbuf[(size_t)b * CAP + i];
        int ld = ((unsigned)ev.x) >> 16;
        int r = atomicAdd(&lcur[ld], 1);
        csr_sw[csr_start + exl[ld] + r] = make_int2(ev.x & 0xFFFF, ev.y);
    }
}

// ---------------- mega-prep: gcnt zero + x->bf16 + all weight prep, 1 dispatch ----------------
constexpr int P_O0 = 256;                     // gcnt zero
constexpr int P_O1 = P_O0 + NN * 64;          // xconvert items
constexpr int P_O2 = P_O1 + 128 * 256;        // w1_0 split
constexpr int P_O3 = P_O2 + 256 * 256;        // w2_0 bn split
constexpr int P_O4 = P_O3 + 256 * 256;        // w1_1 split
constexpr int P_O5 = P_O4 + 256 * 256;        // w2_1 bn split
constexpr int P_O6 = P_O5 + 64 * 256;         // wpad
constexpr int P_O7 = P_O6 + 256;              // bf0
constexpr int P_TOT = P_O7 + 256;             // bf1

__global__ __launch_bounds__(256) void prep_kernel(
    const float* __restrict__ x,
    const float* __restrict__ w1_0, const float* __restrict__ w2_0,
    const float* __restrict__ w1_1, const float* __restrict__ w2_1,
    const float* __restrict__ w1_2,
    const float* __restrict__ b2_0, const float* __restrict__ bng0,
    const float* __restrict__ bnb0, const float* __restrict__ bnm0, const float* __restrict__ bnv0,
    const float* __restrict__ b2_1, const float* __restrict__ bng1,
    const float* __restrict__ bnb1, const float* __restrict__ bnm1, const float* __restrict__ bnv1,
    int* __restrict__ gcnt, u16* __restrict__ xbf,
    u16* __restrict__ w10h, u16* __restrict__ w10l,
    u16* __restrict__ w20h, u16* __restrict__ w20l,
    u16* __restrict__ w11h, u16* __restrict__ w11l,
    u16* __restrict__ w21h, u16* __restrict__ w21l,
    u16* __restrict__ wph,  u16* __restrict__ wpl,
    float* __restrict__ bf0, float* __restrict__ bf1) {
    int i = blockIdx.x * 256 + threadIdx.x;
    if (i >= P_TOT) return;
    if (i >= P_O0 && i < P_O1) {          // x -> bf16 swizzled, 2 cols/item
        int j = i - P_O0;
        int node = j >> 6, col = (j & 63) * 2;
        float2 v = *(const float2*)(x + (size_t)node * 128 + col);
        ushort2 h; h.x = f2bf(v.x); h.y = f2bf(v.y);
        *(ushort2*)(xbf + (size_t)node * 128 + swz(col, node)) = h;
    } else if (i < P_O0) {                // gcnt zero
        gcnt[i] = 0;
    } else if (i < P_O2) {                // w1_0: [128][256] -> T split swizzled
        int j = i - P_O1;
        int k = j >> 8, n = j & 255;
        float v = w1_0[j];
        u16 h = f2bf(v);
        size_t o = (size_t)n * 128 + swz(k, n);
        w10h[o] = h; w10l[o] = f2bf(v - bf2f(h));
    } else if (i < P_O3) {                // w2_0 * bn0 scale
        int j = i - P_O2;
        int k = j >> 8, n = j & 255;
        float sc = bng0[n] * rsqrtf(bnv0[n] + BN_EPS);
        float v = w2_0[j] * sc;
        u16 h = f2bf(v);
        size_t o = (size_t)n * 256 + swz(k, n);
        w20h[o] = h; w20l[o] = f2bf(v - bf2f(h));
    } else if (i < P_O4) {                // w1_1
        int j = i - P_O3;
        int k = j >> 8, n = j & 255;
        float v = w1_1[j];
        u16 h = f2bf(v);
        size_t o = (size_t)n * 256 + swz(k, n);
        w11h[o] = h; w11l[o] = f2bf(v - bf2f(h));
    } else if (i < P_O5) {                // w2_1 * bn1 scale
        int j = i - P_O4;
        int k = j >> 8, n = j & 255;
        float sc = bng1[n] * rsqrtf(bnv1[n] + BN_EPS);
        float v = w2_1[j] * sc;
        u16 h = f2bf(v);
        size_t o = (size_t)n * 256 + swz(k, n);
        w21h[o] = h; w21l[o] = f2bf(v - bf2f(h));
    } else if (i < P_O6) {                // w1_2 padded transposed [64][256]
        int j = i - P_O5;
        int n = j >> 8, k = j & 255;
        float v = (n < 40) ? w1_2[k * 40 + n] : 0.f;
        u16 h = f2bf(v);
        size_t o = (size_t)n * 256 + swz(k, n);
        wph[o] = h; wpl[o] = f2bf(v - bf2f(h));
    } else if (i < P_O7) {                // folded bias 0
        int n = i - P_O6;
        float sc = bng0[n] * rsqrtf(bnv0[n] + BN_EPS);
        bf0[n] = (b2_0[n] - bnm0[n]) * sc + bnb0[n];
    } else {                              // folded bias 1
        int n = i - P_O7;
        float sc = bng1[n] * rsqrtf(bnv1[n] + BN_EPS);
        bf1[n] = (b2_1[n] - bnm1[n]) * sc + bnb1[n];
    }
}

// ---------------- pull aggregation (C=128/256, bf16 pre-swizzled planes) ----------------
template <int C>
__global__ __launch_bounds__(256) void aggregate_kernel(
    const u16* __restrict__ xp,
    const int* __restrict__ row_ptr, const int2* __restrict__ csw,
    u16* __restrict__ outp, int n) {
    constexpr int V = (C == 128) ? 2 : 4;
    int node = blockIdx.x * 4 + (threadIdx.x >> 6);
    if (node >= n) return;
    int lane = threadIdx.x & 63;
    int col = lane * V;
    int beg = row_ptr[node], end = row_ptr[node + 1];

    float acc[V];
    if constexpr (C == 128) {
        ushort2 h = *(const ushort2*)(xp + (size_t)node * C + swz(col, node));
        acc[0] = bf2f(h.x); acc[1] = bf2f(h.y);
    } else {
        ushort4 h = *(const ushort4*)(xp + (size_t)node * C + swz(col, node));
        acc[0] = bf2f(h.x); acc[1] = bf2f(h.y); acc[2] = bf2f(h.z); acc[3] = bf2f(h.w);
    }

    int e = beg;
    for (; e + 8 <= end; e += 8) {
        int2 sw[8];
#pragma unroll
        for (int u = 0; u < 8; u++) sw[u] = csw[e + u];
        if constexpr (C == 128) {
            ushort2 H[8];
#pragma unroll
            for (int u = 0; u < 8; u++) {
                int s = sw[u].x;
                H[u] = *(const ushort2*)(xp + (size_t)s * C + swz(col, s));
            }
#pragma unroll
            for (int u = 0; u < 8; u++) {
                float w = __int_as_float(sw[u].y);
                acc[0] = fmaf(w, bf2f(H[u].x), acc[0]);
                acc[1] = fmaf(w, bf2f(H[u].y), acc[1]);
            }
        } else {
            ushort4 H[8];
#pragma unroll
            for (int u = 0; u < 8; u++) {
                int s = sw[u].x;
                H[u] = *(const ushort4*)(xp + (size_t)s * C + swz(col, s));
            }
#pragma unroll
            for (int u = 0; u < 8; u++) {
                float w = __int_as_float(sw[u].y);
                acc[0] = fmaf(w, bf2f(H[u].x), acc[0]);
                acc[1] = fmaf(w, bf2f(H[u].y), acc[1]);
                acc[2] = fmaf(w, bf2f(H[u].z), acc[2]);
                acc[3] = fmaf(w, bf2f(H[u].w), acc[3]);
            }
        }
    }
    for (; e + 4 <= end; e += 4) {
        int2 sw[4];
#pragma unroll
        for (int u = 0; u < 4; u++) sw[u] = csw[e + u];
        if constexpr (C == 128) {
            ushort2 H[4];
#pragma unroll
            for (int u = 0; u < 4; u++) {
                int s = sw[u].x;
                H[u] = *(const ushort2*)(xp + (size_t)s * C + swz(col, s));
            }
#pragma unroll
            for (int u = 0; u < 4; u++) {
                float w = __int_as_float(sw[u].y);
                acc[0] = fmaf(w, bf2f(H[u].x), acc[0]);
                acc[1] = fmaf(w, bf2f(H[u].y), acc[1]);
            }
        } else {
            ushort4 H[4];
#pragma unroll
            for (int u = 0; u < 4; u++) {
                int s = sw[u].x;
                H[u] = *(const ushort4*)(xp + (size_t)s * C + swz(col, s));
            }
#pragma unroll
            for (int u = 0; u < 4; u++) {
                float w = __int_as_float(sw[u].y);
                acc[0] = fmaf(w, bf2f(H[u].x), acc[0]);
                acc[1] = fmaf(w, bf2f(H[u].y), acc[1]);
                acc[2] = fmaf(w, bf2f(H[u].z), acc[2]);
                acc[3] = fmaf(w, bf2f(H[u].w), acc[3]);
            }
        }
    }
    for (; e < end; ++e) {
        int2 sw = csw[e];
        float w = __int_as_float(sw.y);
        if constexpr (C == 128) {
            ushort2 h = *(const ushort2*)(xp + (size_t)sw.x * C + swz(col, sw.x));
            acc[0] = fmaf(w, bf2f(h.x), acc[0]); acc[1] = fmaf(w, bf2f(h.y), acc[1]);
        } else {
            ushort4 h = *(const ushort4*)(xp + (size_t)sw.x * C + swz(col, sw.x));
            acc[0] = fmaf(w, bf2f(h.x), acc[0]); acc[1] = fmaf(w, bf2f(h.y), acc[1]);
            acc[2] = fmaf(w, bf2f(h.z), acc[2]); acc[3] = fmaf(w, bf2f(h.w), acc[3]);
        }
    }

    if constexpr (C == 128) {
        ushort2 h;
        h.x = f2bf(acc[0]); h.y = f2bf(acc[1]);
        *(ushort2*)(outp + (size_t)node * C + swz(col, node)) = h;
    } else {
        ushort4 h;
        h.x = f2bf(acc[0]); h.y = f2bf(acc[1]); h.z = f2bf(acc[2]); h.w = f2bf(acc[3]);
        *(ushort4*)(outp + (size_t)node * C + swz(col, node)) = h;
    }
}

// ---------------- bf16-A x split-B MFMA GEMM (round-16 grid: m in x, n in y) ----------------
template <int BN_, int EPI, int OUTHL>
__global__ __launch_bounds__(256, 3) void gemm_mfma_kernel(
    const u16* __restrict__ Ahi,
    const u16* __restrict__ Bhi, const u16* __restrict__ Blo,
    float* __restrict__ outf, u16* __restrict__ outhi,
    int M, int K, int LDA, int LDC, int NSTORE,
    const float* __restrict__ bias) {
    constexpr int WGN = (BN_ == 128) ? 2 : 1;
    constexpr int WGM = 4 / WGN;
    constexpr int WTM = 128 / WGM;
    constexpr int MF = WTM / 16;
    constexpr int NF = 4;
    __shared__ __attribute__((aligned(16))) u16 LA[128 * 64];
    __shared__ __attribute__((aligned(16))) u16 LB[2 * BN_ * 64];

    const int tid = threadIdx.x;
    const int lane = tid & 63;
    const int wid = tid >> 6;
    const int wm = wid / WGN, wn = wid % WGN;
    const int m0 = blockIdx.x * 128, n0 = blockIdx.y * BN_;
    const int ln = lane & 15, l4 = lane >> 4;

    f32x4 acc[MF][NF];
#pragma unroll
    for (int mi = 0; mi < MF; mi++)
#pragma unroll
        for (int ni = 0; ni < NF; ni++) acc[mi][ni] = (f32x4){0.f, 0.f, 0.f, 0.f};

    for (int k0 = 0; k0 < K; k0 += 64) {
#pragma unroll
        for (int rep = 0; rep < 4; rep++) {
            int idx = rep * 256 + tid;
            int row = idx >> 3, c16 = idx & 7;
            int gm = m0 + row;
            if (gm > M - 1) gm = M - 1;
            gload16(Ahi + (size_t)gm * LDA + k0 + c16 * 8, &LA[(size_t)(idx - lane) * 8]);
        }
#pragma unroll
        for (int rep = 0; rep < BN_ / 16; rep++) {
            int idx = rep * 256 + tid;
            int plane = idx / (BN_ * 8);
            int rc = idx % (BN_ * 8);
            int row = rc >> 3, c16 = rc & 7;
            const u16* src = plane ? Blo : Bhi;
            gload16(src + (size_t)(n0 + row) * K + k0 + c16 * 8, &LB[(size_t)(idx - lane) * 8]);
        }
        asm volatile("s_waitcnt vmcnt(0)" ::: "memory");
        __syncthreads();

#pragma unroll
        for (int kk = 0; kk < 2; kk++) {
            bf16x8 ah[MF], bh[NF], bl[NF];
#pragma unroll
            for (int mi = 0; mi < MF; mi++) {
                int row = wm * WTM + mi * 16 + ln;
                int slot = (kk * 4 + l4) ^ (row & 7);
                ah[mi] = *(const bf16x8*)&LA[row * 64 + slot * 8];
            }
#pragma unroll
            for (int ni = 0; ni < NF; ni++) {
                int row = wn * 64 + ni * 16 + ln;
                int slot = (kk * 4 + l4) ^ (row & 7);
                bh[ni] = *(const bf16x8*)&LB[row * 64 + slot * 8];
                bl[ni] = *(const bf16x8*)&LB[BN_ * 64 + row * 64 + slot * 8];
            }
#pragma unroll
            for (int mi = 0; mi < MF; mi++)
#pragma unroll
                for (int ni = 0; ni < NF; ni++) {
                    acc[mi][ni] = __builtin_amdgcn_mfma_f32_16x16x32_bf16(ah[mi], bh[ni], acc[mi][ni], 0, 0, 0);
                    acc[mi][ni] = __builtin_amdgcn_mfma_f32_16x16x32_bf16(ah[mi], bl[ni], acc[mi][ni], 0, 0, 0);
                }
        }
        __syncthreads();
    }

#pragma unroll
    for (int ni = 0; ni < NF; ni++) {
        int c = n0 + wn * 64 + ni * 16 + ln;
        float bb = 0.f;
        if constexpr (EPI == 1) bb = bias[c];
        bool cok = (c < NSTORE);
#pragma unroll
        for (int mi = 0; mi < MF; mi++) {
#pragma unroll
            for (int r = 0; r < 4; r++) {
                int row = m0 + wm * WTM + mi * 16 + l4 * 4 + r;
                if (row < M && cok) {
                    float v = acc[mi][ni][r] + bb;
                    if constexpr (EPI == 1) v = fmaxf(v, 0.f);
                    if constexpr (OUTHL == 1) {
                        outhi[(size_t)row * LDC + swz(c, row)] = f2bf(v);
                    } else if constexpr (OUTHL == 2) {
                        size_t o = (size_t)row * LDC + c;
                        outf[o] = v;
                        outhi[o] = f2bf(v);
                    } else {
                        outf[(size_t)row * LDC + c] = v;
                    }
                }
            }
        }
    }
}

// ---------------- fused agg<40> + tail: 6-way edge-parallel gather + shuffle softmax ----------------
__global__ __launch_bounds__(256) void agg40_final_kernel(
    const float* __restrict__ p, const u16* __restrict__ pbf,
    const int* __restrict__ row_ptr, const int2* __restrict__ csw,
    const float* __restrict__ b1, const float* __restrict__ w2,
    const float* __restrict__ b2, float* __restrict__ out, int n) {
    __shared__ float sw[1600], sb1[40], sb2[40];
    __shared__ float tl[4][40];
    for (int i = threadIdx.x; i < 1600; i += 256) sw[i] = w2[i];
    if (threadIdx.x < 40) { sb1[threadIdx.x] = b1[threadIdx.x]; sb2[threadIdx.x] = b2[threadIdx.x]; }
    __syncthreads();

    int w = threadIdx.x >> 6;
    int node = blockIdx.x * 4 + w;
    int lane = threadIdx.x & 63;
    bool valid = node < n;

    int g = lane / 10;
    int cl = lane - g * 10;
    int col = cl * 4;
    float a0 = 0.f, a1 = 0.f, a2 = 0.f, a3 = 0.f;
    if (valid && lane < 60) {
        int beg = row_ptr[node], end = row_ptr[node + 1];
        if (g == 0) {
            float4 sv = *(const float4*)(p + (size_t)node * 40 + col);
            a0 = sv.x; a1 = sv.y; a2 = sv.z; a3 = sv.w;
        }
        int e = beg + g;
        for (; e + 6 < end; e += 12) {
            int2 s0 = csw[e], s1 = csw[e + 6];
            ushort4 h0 = *(const ushort4*)(pbf + (size_t)s0.x * 40 + col);
            ushort4 h1 = *(const ushort4*)(pbf + (size_t)s1.x * 40 + col);
            float w0 = __int_as_float(s0.y), w1 = __int_as_float(s1.y);
            a0 = fmaf(w0, bf2f(h0.x), a0); a1 = fmaf(w0, bf2f(h0.y), a1);
            a2 = fmaf(w0, bf2f(h0.z), a2); a3 = fmaf(w0, bf2f(h0.w), a3);
            a0 = fmaf(w1, bf2f(h1.x), a0); a1 = fmaf(w1, bf2f(h1.y), a1);
            a2 = fmaf(w1, bf2f(h1.z), a2); a3 = fmaf(w1, bf2f(h1.w), a3);
        }
        for (; e < end; e += 6) {
            int2 s0 = csw[e];
            ushort4 h0 = *(const ushort4*)(pbf + (size_t)s0.x * 40 + col);
            float w0 = __int_as_float(s0.y);
            a0 = fmaf(w0, bf2f(h0.x), a0); a1 = fmaf(w0, bf2f(h0.y), a1);
            a2 = fmaf(w0, bf2f(h0.z), a2); a3 = fmaf(w0, bf2f(h0.w), a3);
        }
    }
    a0 += __shfl_down(a0, 30, 64);
    a1 += __shfl_down(a1, 30, 64);
    a2 += __shfl_down(a2, 30, 64);
    a3 += __shfl_down(a3, 30, 64);
    {
        float b0 = __shfl_down(a0, 10, 64), c0 = __shfl_down(a0, 20, 64);
        float b1v = __shfl_down(a1, 10, 64), c1 = __shfl_down(a1, 20, 64);
        float b2v = __shfl_down(a2, 10, 64), c2 = __shfl_down(a2, 20, 64);
        float b3 = __shfl_down(a3, 10, 64), c3 = __shfl_down(a3, 20, 64);
        a0 += b0 + c0;
        a1 += b1v + c1;
        a2 += b2v + c2;
        a3 += b3 + c3;
    }
    if (valid && lane < 10) {
        tl[w][col + 0] = fmaxf(a0 + sb1[col + 0], 0.f);
        tl[w][col + 1] = fmaxf(a1 + sb1[col + 1], 0.f);
        tl[w][col + 2] = fmaxf(a2 + sb1[col + 2], 0.f);
        tl[w][col + 3] = fmaxf(a3 + sb1[col + 3], 0.f);
    }
    __syncthreads();

    float y = -1e30f;
    if (valid && lane < 40) {
        y = sb2[lane];
#pragma unroll 8
        for (int k = 0; k < 40; k++) y = fmaf(tl[w][k], sw[k * 40 + lane], y);
    }
    float m = y;
#pragma unroll
    for (int o = 32; o > 0; o >>= 1) m = fmaxf(m, __shfl_xor(m, o, 64));
    float ex = (lane < 40) ? expf(y - m) : 0.f;
    float s = ex;
#pragma unroll
    for (int o = 32; o > 0; o >>= 1) s += __shfl_xor(s, o, 64);
    if (valid && lane < 40)
        out[(size_t)node * 40 + lane] = y - m - logf(s);
}

extern "C" void kernel_launch(void* const* d_in, const int* in_sizes, int n_in,
                              void* d_out, int out_size, void* d_ws, size_t ws_size,
                              hipStream_t stream) {
    const float* x    = (const float*)d_in[0];
    const int*   ei   = (const int*)d_in[1];  // int64 in ref -> int32 on device
    const float* ew   = (const float*)d_in[2];
    const float* w1_0 = (const float*)d_in[3],  *b1_0 = (const float*)d_in[4];
    const float* w2_0 = (const float*)d_in[5],  *b2_0 = (const float*)d_in[6];
    const float* w1_1 = (const float*)d_in[7],  *b1_1 = (const float*)d_in[8];
    const float* w2_1 = (const float*)d_in[9],  *b2_1 = (const float*)d_in[10];
    const float* w1_2 = (const float*)d_in[11], *b1_2 = (const float*)d_in[12];
    const float* w2_2 = (const float*)d_in[13], *b2_2 = (const float*)d_in[14];
    const float* bng0 = (const float*)d_in[15], *bnb0 = (const float*)d_in[16];
    const float* bnm0 = (const float*)d_in[17], *bnv0 = (const float*)d_in[18];
    const float* bng1 = (const float*)d_in[19], *bnb1 = (const float*)d_in[20];
    const float* bnm1 = (const float*)d_in[21], *bnv1 = (const float*)d_in[22];
    float* out = (float*)d_out;

    char* wsp = (char*)d_ws;
    size_t off = 0;
    auto alloc = [&](size_t bytes) -> char* {
        char* p = wsp + off;
        off += (bytes + 255) & ~(size_t)255;
        return p;
    };
    int*   gcnt    = (int*)alloc(256 * sizeof(int));
    int*   row_ptr = (int*)alloc((size_t)(NN + 1) * sizeof(int));
    int2*  bbuf    = (int2*)alloc((size_t)NBUK * CAP * sizeof(int2));   // 10.24 MB
    int2*  csr_sw  = (int2*)alloc((size_t)NE * sizeof(int2));
    u16* xbf   = (u16*)alloc((size_t)NN * 128 * sizeof(u16));
    u16* h0agg = (u16*)alloc((size_t)NN * 128 * sizeof(u16));
    u16* bufA  = (u16*)alloc((size_t)NN * 256 * sizeof(u16));
    u16* bufB  = (u16*)alloc((size_t)NN * 256 * sizeof(u16));
    u16* w10h = (u16*)alloc(128 * 256 * 2); u16* w10l = (u16*)alloc(128 * 256 * 2);
    u16* w20h = (u16*)alloc(256 * 256 * 2); u16* w20l = (u16*)alloc(256 * 256 * 2);
    u16* w11h = (u16*)alloc(256 * 256 * 2); u16* w11l = (u16*)alloc(256 * 256 * 2);
    u16* w21h = (u16*)alloc(256 * 256 * 2); u16* w21l = (u16*)alloc(256 * 256 * 2);
    u16* wph  = (u16*)alloc(64 * 256 * 2);  u16* wpl  = (u16*)alloc(64 * 256 * 2);
    float* bf0 = (float*)alloc(256 * sizeof(float));
    float* bf1 = (float*)alloc(256 * sizeof(float));

    // --- 1 dispatch: gcnt zero + x convert + all weight prep ---
    prep_kernel<<<(P_TOT + 255) / 256, 256, 0, stream>>>(
        x, w1_0, w2_0, w1_1, w2_1, w1_2,
        b2_0, bng0, bnb0, bnm0, bnv0,
        b2_1, bng1, bnb1, bnm1, bnv1,
        gcnt, xbf, w10h, w10l, w20h, w20l, w11h, w11l, w21h, w21l,
        wph, wpl, bf0, bf1);

    // --- CSR build: 2-pass binned counting sort (replaces 4 dispatches) ---
    partition_kernel<<<(NE + EPB - 1) / EPB, 256, 0, stream>>>(ei, ew, gcnt, bbuf, NE);
    bucket_sort_kernel<<<NBUK, 256, 0, stream>>>(gcnt, bbuf, row_ptr, csr_sw);

    const int aggBlocks = (NN + 3) / 4;
    dim3 gBig((NN + 127) / 128, 2);
    dim3 gSm((NN + 127) / 128, 1);

    // ---- layer 0 ----
    aggregate_kernel<128><<<aggBlocks, 256, 0, stream>>>(xbf, row_ptr, csr_sw, h0agg, NN);
    gemm_mfma_kernel<128, 1, 1><<<gBig, 256, 0, stream>>>(
        h0agg, w10h, w10l, nullptr, bufA, NN, 128, 128, 256, 256, b1_0);
    gemm_mfma_kernel<128, 1, 1><<<gBig, 256, 0, stream>>>(
        bufA, w20h, w20l, nullptr, bufB, NN, 256, 256, 256, 256, bf0);

    // ---- layer 1 ----
    aggregate_kernel<256><<<aggBlocks, 256, 0, stream>>>(bufB, row_ptr, csr_sw, bufA, NN);
    gemm_mfma_kernel<128, 1, 1><<<gBig, 256, 0, stream>>>(
        bufA, w11h, w11l, nullptr, bufB, NN, 256, 256, 256, 256, b1_1);
    gemm_mfma_kernel<128, 1, 1><<<gBig, 256, 0, stream>>>(
        bufB, w21h, w21l, nullptr, bufA, NN, 256, 256, 256, 256, bf1);

    // ---- layer 2 (reordered: p = h @ w1_2, then fused agg40+tail) ----
    float* p   = (float*)bufB;
    u16*   pbf = bufB + 4194304;             // 8 MB offset (u16 elements)
    gemm_mfma_kernel<64, 0, 2><<<gSm, 256, 0, stream>>>(
        bufA, wph, wpl, p, pbf, NN, 256, 256, 40, 40, nullptr);
    agg40_final_kernel<<<aggBlocks, 256, 0, stream>>>(
        p, pbf, row_ptr, csr_sw, b1_2, w2_2, b2_2, out, NN);
}